// Round 17
// baseline (105.269 us; speedup 1.0000x reference)
//
#include <hip/hip_runtime.h>
#include <stdint.h>

#define TNUM 2048
#define DDIM 1024
#define NEXP 8
#define KSEL 2
#define IDIM 1024
#define TWOI 2048
#define LIMITV 7.0f
#define ALPHAV 1.702f
#define ROWT_MAX 40   // sum_e ceil(n_e/128) <= 39 < 40 (provable)
#define RMSB (TNUM / 4)               // 512 rms blocks (wave-per-token)
#define N81 (NEXP * TWOI * DDIM / 8)  // w1 8-float groups = 2097152
#define N82 (NEXP * DDIM * IDIM / 8)  // w2 8-float groups = 1048576
#define G1TOT (ROWT_MAX * (TWOI / 128))  // 640 gemm1 tile slots
#define G2TOT (2 * ROWT_MAX * (DDIM / 128))  // 640 gemm2 slots (K-split x2)

typedef __attribute__((ext_vector_type(8))) short bf16x8;
typedef __attribute__((ext_vector_type(4))) float f32x4;

#define VMCNT4() asm volatile("s_waitcnt vmcnt(4)" ::: "memory")
#define VMCNT0() asm volatile("s_waitcnt vmcnt(0)" ::: "memory")
#define BARRIER() asm volatile("s_barrier" ::: "memory")
#define WGBAR() __builtin_amdgcn_s_barrier()
#define SCHEDB() __builtin_amdgcn_sched_barrier(0)

__device__ __forceinline__ unsigned short f2bf(float f) {
  unsigned u = __float_as_uint(f);
  u += 0x7FFF + ((u >> 16) & 1);   // round-to-nearest-even
  return (unsigned short)(u >> 16);
}

__device__ __forceinline__ int4 cvt8(float4 a, float4 b) {
  union { unsigned short us[8]; int4 v; } o;
  o.us[0] = f2bf(a.x); o.us[1] = f2bf(a.y); o.us[2] = f2bf(a.z); o.us[3] = f2bf(a.w);
  o.us[4] = f2bf(b.x); o.us[5] = f2bf(b.y); o.us[6] = f2bf(b.z); o.us[7] = f2bf(b.w);
  return o.v;
}

__device__ __forceinline__ float4 ld4bf(const unsigned short* p) {
  int2 v = *(const int2*)p;
  unsigned a = (unsigned)v.x, b = (unsigned)v.y;
  float4 r;
  r.x = __uint_as_float((a & 0xFFFFu) << 16);
  r.y = __uint_as_float(a & 0xFFFF0000u);
  r.z = __uint_as_float((b & 0xFFFFu) << 16);
  r.w = __uint_as_float(b & 0xFFFF0000u);
  return r;
}

// Direct global->LDS async copy, 16B per lane (m97/m193 recipe).
__device__ __forceinline__ void gl2lds16(const void* g, void* l) {
  __builtin_amdgcn_global_load_lds(
      (__attribute__((address_space(1))) unsigned int*)(uintptr_t)g,
      (__attribute__((address_space(3))) unsigned int*)(uintptr_t)l, 16, 0, 0);
}

// Bijective chunked XCD swizzle (m204).
__device__ __forceinline__ int xcd_swz(int bid, int total) {
  int q = total >> 3, r = total & 7;
  int xcd = bid & 7, pos = bid >> 3;
  return (xcd < r ? xcd * (q + 1) : r * (q + 1) + (xcd - r) * q) + pos;
}

// ---------------- K1: RMSNorm + gate + top-2 (wave/token) ∥ w1 fp32->bf16 -----
__global__ __launch_bounds__(256) void k_rms_cvt(
    const float* __restrict__ x, const float* __restrict__ norm_w,
    const float* __restrict__ gate_w, const float* __restrict__ gate_b,
    const float* __restrict__ w1f, unsigned short* __restrict__ w1b,
    unsigned short* __restrict__ hb, int* __restrict__ tidx,
    float* __restrict__ twt) {
  if ((int)blockIdx.x >= RMSB) {
    // weight-conversion role: four 8-float groups per thread
    int k0 = ((int)blockIdx.x - RMSB) * 1024 + (int)threadIdx.x;
    const float4* s = (const float4*)w1f;
#pragma unroll
    for (int i = 0; i < 4; ++i) {
      int k = k0 + i * 256;
      if (k < N81) ((int4*)w1b)[k] = cvt8(s[2 * k], s[2 * k + 1]);
    }
    return;
  }
  const int lane = threadIdx.x & 63;
  const int t = blockIdx.x * 4 + (threadIdx.x >> 6);

  const float4* xr  = (const float4*)x + (size_t)t * 256 + lane * 4;
  const float4* nwr = (const float4*)norm_w + lane * 4;
  const float4* gbr = (const float4*)gate_b;
  float4 xv[4], nwv[4];
#pragma unroll
  for (int i = 0; i < 4; ++i) xv[i] = xr[i];
  float4 gb0 = gbr[0], gb1 = gbr[1];
#pragma unroll
  for (int i = 0; i < 4; ++i) nwv[i] = nwr[i];

  float ss = 0.f;
#pragma unroll
  for (int i = 0; i < 4; ++i)
    ss += xv[i].x * xv[i].x + xv[i].y * xv[i].y + xv[i].z * xv[i].z + xv[i].w * xv[i].w;
#pragma unroll
  for (int m = 1; m < 64; m <<= 1) ss += __shfl_xor(ss, m);
  const float sc = rsqrtf(ss * (1.0f / DDIM) + 1.1920929e-07f);

  float4 h[4];
#pragma unroll
  for (int i = 0; i < 4; ++i) {
    h[i].x = xv[i].x * sc * nwv[i].x;
    h[i].y = xv[i].y * sc * nwv[i].y;
    h[i].z = xv[i].z * sc * nwv[i].z;
    h[i].w = xv[i].w * sc * nwv[i].w;
  }
  int4* hw = (int4*)(hb + (size_t)t * DDIM + lane * 16);
  hw[0] = cvt8(h[0], h[1]);
  hw[1] = cvt8(h[2], h[3]);

  float p[NEXP];
#pragma unroll
  for (int e = 0; e < NEXP; ++e) {
    const float4* g4 = (const float4*)gate_w + e * 256 + lane * 4;
    float4 a = g4[0], b = g4[1], c = g4[2], d = g4[3];
    p[e] = h[0].x * a.x + h[0].y * a.y + h[0].z * a.z + h[0].w * a.w
         + h[1].x * b.x + h[1].y * b.y + h[1].z * b.z + h[1].w * b.w
         + h[2].x * c.x + h[2].y * c.y + h[2].z * c.z + h[2].w * c.w
         + h[3].x * d.x + h[3].y * d.y + h[3].z * d.z + h[3].w * d.w;
  }
#pragma unroll
  for (int m = 1; m < 64; m <<= 1) {
#pragma unroll
    for (int e = 0; e < NEXP; ++e) p[e] += __shfl_xor(p[e], m);
  }
  p[0] += gb0.x; p[1] += gb0.y; p[2] += gb0.z; p[3] += gb0.w;
  p[4] += gb1.x; p[5] += gb1.y; p[6] += gb1.z; p[7] += gb1.w;

  if (lane == 0) {
    int i0 = 0; float v0 = p[0];
#pragma unroll
    for (int e = 1; e < NEXP; ++e) if (p[e] > v0) { v0 = p[e]; i0 = e; }
    int i1 = -1; float v1 = -3.4e38f;
#pragma unroll
    for (int e = 0; e < NEXP; ++e) if (e != i0 && p[e] > v1) { v1 = p[e]; i1 = e; }
    float e1 = __expf(v1 - v0);
    float w0 = 1.f / (1.f + e1);
    int2 ip; ip.x = i0; ip.y = i1;
    float2 wp; wp.x = w0; wp.y = e1 * w0;
    ((int2*)tidx)[t] = ip;
    ((float2*)twt)[t] = wp;
  }
}

// ---------------- K2: scheduler — deterministic, wave-parallel scan -----------
__global__ __launch_bounds__(512) void k_sched(
    const int* __restrict__ tidx, int* __restrict__ meta,
    int* __restrict__ tl, int* __restrict__ rows, int* __restrict__ sof) {
  __shared__ unsigned short cnt[256][NEXP];   // 4 KB
  __shared__ int off[NEXP];
  __shared__ int tot[NEXP];
  const int tid = threadIdx.x;
  int e_[16], rel_[16];
  if (tid < 256) {
#pragma unroll
    for (int k = 0; k < 16; ++k) e_[k] = tidx[tid * 16 + k];
#pragma unroll
    for (int k = 0; k < 16; ++k) {
      int r = 0;
#pragma unroll
      for (int j2 = 0; j2 < 16; ++j2)
        if (j2 < k) r += (e_[j2] == e_[k]) ? 1 : 0;
      rel_[k] = r;
    }
#pragma unroll
    for (int e = 0; e < NEXP; ++e) {
      int c = 0;
#pragma unroll
      for (int k = 0; k < 16; ++k) c += (e_[k] == e) ? 1 : 0;
      cnt[tid][e] = (unsigned short)c;
    }
  }
  __syncthreads();
  // wave-parallel exclusive scan: wave `we` scans expert `we`'s 256 counts
  {
    const int we = tid >> 6, lane = tid & 63;
    int carry = 0;
#pragma unroll
    for (int chunk = 0; chunk < 4; ++chunk) {
      int i = chunk * 64 + lane;
      int c = (int)cnt[i][we];
      int s = c;
#pragma unroll
      for (int o = 1; o < 64; o <<= 1) {
        int t2 = __shfl_up(s, o);
        if (lane >= o) s += t2;
      }
      cnt[i][we] = (unsigned short)(s - c + carry);  // exclusive prefix
      carry += __shfl(s, 63);
    }
    if (lane == 0) tot[we] = carry;
  }
  __syncthreads();
  if (tid == 0) {
    int acc = 0, nt = 0;
    for (int e = 0; e < NEXP; ++e) {
      meta[8 + e] = acc; off[e] = acc;
      int c = tot[e]; acc += c;
      int ntile = (c + 127) >> 7;
      for (int r = 0; r < ntile; ++r) tl[nt++] = (e << 8) | r;
    }
    meta[16] = acc;
    meta[25] = nt;
  }
  __syncthreads();
  if (tid < 256) {
#pragma unroll
    for (int k = 0; k < 16; ++k) {
      int i = tid * 16 + k;
      int e = e_[k];
      int slot = off[e] + (int)cnt[tid][e] + rel_[k];
      rows[slot] = i >> 1;
      sof[i] = slot;
    }
  }
}

// ---------------- K4: GEMM1, BK=32 dbuf + counted vmcnt + FULL FENCES ---------
// 32 KB LDS: double-buffer AND 4 blocks/CU. Per step: issue next stage (4
// loads), vmcnt(4) waits only for CURRENT buffer's loads (next stays in
// flight). Sync via builtin s_barrier + sched_barrier(0) fences (rule #18:
// asm "memory" clobber does NOT order LDS ops; sched_barrier does).
__global__ __launch_bounds__(256, 4) void k_gemm1(
    const unsigned short* __restrict__ hb, const unsigned short* __restrict__ w1b,
    const float* __restrict__ mlp1_b, const int* __restrict__ meta,
    const int* __restrict__ tl, const int* __restrict__ rows,
    const float* __restrict__ w2f, unsigned short* __restrict__ w2b,
    unsigned short* __restrict__ actb) {
  const int bid = blockIdx.x;
  const int tid = threadIdx.x, lane = tid & 63, wid = tid >> 6;
  if (bid >= G1TOT) {
    // w2 conversion role: four 8-float groups per thread
    int k0 = (bid - G1TOT) * 1024 + tid;
    const float4* s = (const float4*)w2f;
#pragma unroll
    for (int i = 0; i < 4; ++i) {
      int k = k0 + i * 256;
      if (k < N82) ((int4*)w2b)[k] = cvt8(s[2 * k], s[2 * k + 1]);
    }
    return;
  }
  const int nt = meta[25];
  const int total = nt * (TWOI / 128);
  if (bid >= total) return;
  const int j = xcd_swz(bid, total);
  const int ct = j / nt;
  const int tile = tl[j - ct * nt];
  const int e = tile >> 8, rt = tile & 255;
  const int offs = meta[8 + e];
  const int n_e = meta[9 + e] - offs;

  __shared__ unsigned short As[2][128][32];   // 8 KB x2
  __shared__ unsigned short Bs[2][128][32];   // 8 KB x2
  __shared__ int srow[128];
  if (tid < 128) srow[tid] = rows[offs + min(rt * 128 + tid, n_e - 1)];
  __syncthreads();

  // staging: slot s = j*256+tid -> LDS elems s*8; row = s>>2, col chunk tid&3;
  // source col XOR-swizzled by row&3 (both-sides swizzle, rule #21).
  const int r0  = tid >> 2;                       // 0..63
  const int csw = (((tid & 3) ^ (r0 & 3)) << 3);  // elem offset in 32-col row
  const unsigned short* w1e = w1b + (size_t)e * TWOI * DDIM;
  const unsigned short* gA0 = hb + (size_t)srow[r0] * DDIM + csw;
  const unsigned short* gA1 = hb + (size_t)srow[64 + r0] * DDIM + csw;
  const unsigned short* gB0 = w1e + (size_t)(ct * 128 + r0) * DDIM + csw;
  const unsigned short* gB1 = w1e + (size_t)(ct * 128 + 64 + r0) * DDIM + csw;

#define G1_STAGE(BUF, KT) {                                                    \
    gl2lds16(gA0 + (KT) * 32, &As[BUF][0][0] + tid * 8);                       \
    gl2lds16(gA1 + (KT) * 32, &As[BUF][0][0] + 2048 + tid * 8);                \
    gl2lds16(gB0 + (KT) * 32, &Bs[BUF][0][0] + tid * 8);                       \
    gl2lds16(gB1 + (KT) * 32, &Bs[BUF][0][0] + 2048 + tid * 8);                \
  }

  f32x4 acc[4][4];
#pragma unroll
  for (int m = 0; m < 4; ++m)
#pragma unroll
    for (int n = 0; n < 4; ++n) acc[m][n] = (f32x4){0.f, 0.f, 0.f, 0.f};

  const int wr = wid >> 1, wc = wid & 1;
  const int lrow = lane & 15, kgrp = lane >> 4;   // kgrp = K-chunk 0..3
  const int NK = DDIM / 32;                       // 32 steps

  G1_STAGE(0, 0)
#pragma unroll
  for (int kt = 0; kt < NK; ++kt) {
    const int cur = kt & 1;
    if (kt + 1 < NK) {
      G1_STAGE(cur ^ 1, kt + 1)
      SCHEDB();
      VMCNT4();       // current buffer's 4 loads landed; next 4 stay in flight
    } else {
      VMCNT0();
    }
    SCHEDB();
    WGBAR();
    SCHEDB();
    bf16x8 af[4], bfr[4];
#pragma unroll
    for (int m = 0; m < 4; ++m) {
      int row = wr * 64 + m * 16 + lrow;
      int chunk = kgrp ^ (row & 3);
      af[m] = *(const bf16x8*)&As[cur][row][chunk * 8];
    }
#pragma unroll
    for (int n = 0; n < 4; ++n) {
      int row = wc * 64 + n * 16 + lrow;
      int chunk = kgrp ^ (row & 3);
      bfr[n] = *(const bf16x8*)&Bs[cur][row][chunk * 8];
    }
#pragma unroll
    for (int m = 0; m < 4; ++m)
#pragma unroll
      for (int n = 0; n < 4; ++n)
        acc[m][n] = __builtin_amdgcn_mfma_f32_16x16x32_bf16(af[m], bfr[n], acc[m][n], 0, 0, 0);
    SCHEDB();
    WGBAR();
    SCHEDB();
  }
#undef G1_STAGE

  const float* b1e = mlp1_b + e * TWOI;
#pragma unroll
  for (int m = 0; m < 4; ++m) {
#pragma unroll
    for (int n = 0; n < 4; ++n) {
      int cg = ct * 128 + wc * 64 + n * 16 + (lane & 15);
      float bias = b1e[cg];
#pragma unroll
      for (int j2 = 0; j2 < 4; ++j2) {
        float val = acc[m][n][j2] + bias;
        float part = __shfl_xor(val, 1);
        int rl = wr * 64 + m * 16 + ((lane >> 4) << 2) + j2;
        if (!(lane & 1)) {
          float glu = fminf(val, LIMITV);
          float lin = fminf(fmaxf(part, -LIMITV), LIMITV);
          float s = 1.f / (1.f + __expf(-ALPHAV * glu));
          float a = glu * s * (lin + 1.f);
          if (rt * 128 + rl < n_e)
            actb[(size_t)(offs + rt * 128 + rl) * IDIM + (cg >> 1)] = f2bf(a);
        }
      }
    }
  }
}

// ---------------- K5: GEMM2, K-split x2, single-buffered, 4 blocks/CU ---------
__global__ __launch_bounds__(256, 4) void k_gemm2(
    const unsigned short* __restrict__ actb, const unsigned short* __restrict__ w2b,
    const float* __restrict__ mlp2_b, const int* __restrict__ meta,
    const int* __restrict__ tl, unsigned short* __restrict__ ybuf) {
  const int nt = meta[25];
  const int totalK = nt * (DDIM / 128) * 2;
  const int bid = blockIdx.x;
  if (bid >= totalK) return;
  const int j = xcd_swz(bid, totalK);
  const int kp = j & 1;          // K half: 0 -> [0,512), 1 -> [512,1024)
  const int jt = j >> 1;
  const int ct = jt / nt;
  const int tile = tl[jt - ct * nt];
  const int e = tile >> 8, rt = tile & 255;
  const int offs = meta[8 + e];
  const int n_e = meta[9 + e] - offs;
  const int tid = threadIdx.x, lane = tid & 63, wid = tid >> 6;

  __shared__ unsigned short As[128][64];
  __shared__ unsigned short Bs[128][64];

  const int rloc = tid >> 3;
  const int csw  = (((tid & 7) ^ (rloc & 7)) << 3);
  const int koff = kp * 512;     // element offset into K
  const unsigned short* gA[4];
  const unsigned short* gB[4];
  const unsigned short* w2e = w2b + (size_t)e * DDIM * IDIM;
#pragma unroll
  for (int jj = 0; jj < 4; ++jj) {
    gA[jj] = actb + (size_t)(offs + min(rt * 128 + jj * 32 + rloc, n_e - 1)) * IDIM + koff + csw;
    gB[jj] = w2e + (size_t)(ct * 128 + jj * 32 + rloc) * IDIM + koff + csw;
  }

#define G2_STAGE(KT)                                                           \
  _Pragma("unroll") for (int jj = 0; jj < 4; ++jj) {                           \
    gl2lds16(gA[jj] + (KT) * 64, &As[0][0] + jj * 2048 + tid * 8);             \
    gl2lds16(gB[jj] + (KT) * 64, &Bs[0][0] + jj * 2048 + tid * 8);             \
  }

  f32x4 acc[4][4];
#pragma unroll
  for (int m = 0; m < 4; ++m)
#pragma unroll
    for (int n = 0; n < 4; ++n) acc[m][n] = (f32x4){0.f, 0.f, 0.f, 0.f};

  const int wr = wid >> 1, wc = wid & 1;
  const int lrow = lane & 15, ksub = (lane >> 4) * 8;
  const int NK = 512 / 64;   // 8 K-steps per half

#pragma unroll
  for (int kt = 0; kt < NK; ++kt) {
    G2_STAGE(kt)
    VMCNT0();
    BARRIER();
#pragma unroll
    for (int kk = 0; kk < 2; ++kk) {
      bf16x8 af[4], bfr[4];
#pragma unroll
      for (int m = 0; m < 4; ++m) {
        int row = wr * 64 + m * 16 + lrow;
        int chunk = ((kk * 32 + ksub) >> 3) ^ (row & 7);
        af[m] = *(const bf16x8*)&As[row][chunk * 8];
      }
#pragma unroll
      for (int n = 0; n < 4; ++n) {
        int row = wc * 64 + n * 16 + lrow;
        int chunk = ((kk * 32 + ksub) >> 3) ^ (row & 7);
        bfr[n] = *(const bf16x8*)&Bs[row][chunk * 8];
      }
#pragma unroll
      for (int m = 0; m < 4; ++m)
#pragma unroll
        for (int n = 0; n < 4; ++n)
          acc[m][n] = __builtin_amdgcn_mfma_f32_16x16x32_bf16(af[m], bfr[n], acc[m][n], 0, 0, 0);
    }
    BARRIER();
  }
#undef G2_STAGE

  const float* b2e = mlp2_b + e * DDIM;
  unsigned short* yh = ybuf + (size_t)kp * TNUM * KSEL * DDIM;
#pragma unroll
  for (int m = 0; m < 4; ++m) {
#pragma unroll
    for (int n = 0; n < 4; ++n) {
      int d = ct * 128 + wc * 64 + n * 16 + (lane & 15);
      float bias = kp ? 0.f : b2e[d];
#pragma unroll
      for (int j2 = 0; j2 < 4; ++j2) {
        int rl = wr * 64 + m * 16 + ((lane >> 4) << 2) + j2;
        if (rt * 128 + rl < n_e)
          yh[(size_t)(offs + rt * 128 + rl) * DDIM + d] = f2bf(acc[m][n][j2] + bias);
      }
    }
  }
}

// ---------------- K6: combine (sums 2 K-partials per slot, no atomics) --------
__global__ __launch_bounds__(256) void k_combine(
    const float* __restrict__ x, const unsigned short* __restrict__ ybuf,
    const int* __restrict__ sof, const float* __restrict__ twt,
    float* __restrict__ out) {
  int t = blockIdx.x, tid = threadIdx.x;
  int s0 = sof[2 * t], s1 = sof[2 * t + 1];
  float w0 = twt[2 * t], w1 = twt[2 * t + 1];
  const size_t H = (size_t)TNUM * KSEL * DDIM;
  float4 xv = ((const float4*)x)[t * 256 + tid];
  float4 a0 = ld4bf(ybuf + (size_t)s0 * DDIM + tid * 4);
  float4 a1 = ld4bf(ybuf + H + (size_t)s0 * DDIM + tid * 4);
  float4 b0 = ld4bf(ybuf + (size_t)s1 * DDIM + tid * 4);
  float4 b1 = ld4bf(ybuf + H + (size_t)s1 * DDIM + tid * 4);
  float4 o;
  o.x = xv.x + w0 * (a0.x + a1.x) + w1 * (b0.x + b1.x);
  o.y = xv.y + w0 * (a0.y + a1.y) + w1 * (b0.y + b1.y);
  o.z = xv.z + w0 * (a0.z + a1.z) + w1 * (b0.z + b1.z);
  o.w = xv.w + w0 * (a0.w + a1.w) + w1 * (b0.w + b1.w);
  ((float4*)out)[t * 256 + tid] = o;
}

extern "C" void kernel_launch(void* const* d_in, const int* in_sizes, int n_in,
                              void* d_out, int out_size, void* d_ws, size_t ws_size,
                              hipStream_t stream) {
  const float* x      = (const float*)d_in[0];
  const float* norm_w = (const float*)d_in[1];
  const float* gate_w = (const float*)d_in[2];
  const float* gate_b = (const float*)d_in[3];
  const float* mlp1_w = (const float*)d_in[4];
  const float* mlp1_b = (const float*)d_in[5];
  const float* mlp2_w = (const float*)d_in[6];
  const float* mlp2_b = (const float*)d_in[7];
  float* out = (float*)d_out;

  char* w = (char*)d_ws;
  unsigned short* w1b = (unsigned short*)w; w += (size_t)NEXP * TWOI * DDIM * 2;
  unsigned short* w2b = (unsigned short*)w; w += (size_t)NEXP * DDIM * IDIM * 2;
  unsigned short* hb  = (unsigned short*)w; w += (size_t)TNUM * DDIM * 2;
  unsigned short* actb = (unsigned short*)w; w += (size_t)TNUM * KSEL * IDIM * 2;
  unsigned short* ybuf = (unsigned short*)w; w += (size_t)2 * TNUM * KSEL * DDIM * 2;
  int*   tidx = (int*)w;  w += TNUM * KSEL * 4;
  float* twt  = (float*)w; w += TNUM * KSEL * 4;
  int*   sof  = (int*)w;  w += TNUM * KSEL * 4;
  int*   rows = (int*)w;  w += TNUM * KSEL * 4;
  int*   meta = (int*)w;  w += 32 * 4;
  int*   tl   = (int*)w;  w += 64 * 4;

  k_rms_cvt<<<RMSB + N81 / 1024, 256, 0, stream>>>(x, norm_w, gate_w, gate_b,
                                                   mlp1_w, w1b, hb, tidx, twt);
  k_sched<<<1, 512, 0, stream>>>(tidx, meta, tl, rows, sof);
  k_gemm1<<<G1TOT + N82 / 1024, 256, 0, stream>>>(hb, w1b, mlp1_b, meta, tl, rows,
                                                  mlp2_w, w2b, actb);
  k_gemm2<<<G2TOT, 256, 0, stream>>>(actb, w2b, mlp2_b, meta, tl, ybuf);
  k_combine<<<TNUM, 256, 0, stream>>>(x, ybuf, sof, twt, out);
}

// Round 18
// 104.592 us; speedup vs baseline: 1.0065x; 1.0065x over previous
//
#include <hip/hip_runtime.h>
#include <stdint.h>

#define TNUM 2048
#define DDIM 1024
#define NEXP 8
#define KSEL 2
#define IDIM 1024
#define TWOI 2048
#define LIMITV 7.0f
#define ALPHAV 1.702f
#define ROWT_MAX 40   // sum_e ceil(n_e/128) <= 39 < 40 (provable)
#define RMSB (TNUM / 4)               // 512 rms blocks (wave-per-token)
#define N81 (NEXP * TWOI * DDIM / 8)  // w1 8-float groups = 2097152
#define N82 (NEXP * DDIM * IDIM / 8)  // w2 8-float groups = 1048576
#define G1TOT (ROWT_MAX * (TWOI / 128))  // 640 gemm1 tile slots
#define G2TOT (2 * ROWT_MAX * (DDIM / 128))  // 640 gemm2 slots (K-split x2)

typedef __attribute__((ext_vector_type(8))) short bf16x8;
typedef __attribute__((ext_vector_type(4))) float f32x4;

#define VMCNT4() asm volatile("s_waitcnt vmcnt(4)" ::: "memory")
#define VMCNT0() asm volatile("s_waitcnt vmcnt(0)" ::: "memory")
#define BARRIER() asm volatile("s_barrier" ::: "memory")
#define WGBAR() __builtin_amdgcn_s_barrier()
#define SCHEDB() __builtin_amdgcn_sched_barrier(0)

__device__ __forceinline__ unsigned short f2bf(float f) {
  unsigned u = __float_as_uint(f);
  u += 0x7FFF + ((u >> 16) & 1);   // round-to-nearest-even
  return (unsigned short)(u >> 16);
}

__device__ __forceinline__ int4 cvt8(float4 a, float4 b) {
  union { unsigned short us[8]; int4 v; } o;
  o.us[0] = f2bf(a.x); o.us[1] = f2bf(a.y); o.us[2] = f2bf(a.z); o.us[3] = f2bf(a.w);
  o.us[4] = f2bf(b.x); o.us[5] = f2bf(b.y); o.us[6] = f2bf(b.z); o.us[7] = f2bf(b.w);
  return o.v;
}

__device__ __forceinline__ float4 ld4bf(const unsigned short* p) {
  int2 v = *(const int2*)p;
  unsigned a = (unsigned)v.x, b = (unsigned)v.y;
  float4 r;
  r.x = __uint_as_float((a & 0xFFFFu) << 16);
  r.y = __uint_as_float(a & 0xFFFF0000u);
  r.z = __uint_as_float((b & 0xFFFFu) << 16);
  r.w = __uint_as_float(b & 0xFFFF0000u);
  return r;
}

// Direct global->LDS async copy, 16B per lane (m97/m193 recipe).
__device__ __forceinline__ void gl2lds16(const void* g, void* l) {
  __builtin_amdgcn_global_load_lds(
      (__attribute__((address_space(1))) unsigned int*)(uintptr_t)g,
      (__attribute__((address_space(3))) unsigned int*)(uintptr_t)l, 16, 0, 0);
}

// Bijective chunked XCD swizzle (m204).
__device__ __forceinline__ int xcd_swz(int bid, int total) {
  int q = total >> 3, r = total & 7;
  int xcd = bid & 7, pos = bid >> 3;
  return (xcd < r ? xcd * (q + 1) : r * (q + 1) + (xcd - r) * q) + pos;
}

// ---------------- K1: RMSNorm + gate + top-2 (wave/token) ∥ w1 fp32->bf16 -----
__global__ __launch_bounds__(256) void k_rms_cvt(
    const float* __restrict__ x, const float* __restrict__ norm_w,
    const float* __restrict__ gate_w, const float* __restrict__ gate_b,
    const float* __restrict__ w1f, unsigned short* __restrict__ w1b,
    unsigned short* __restrict__ hb, int* __restrict__ tidx,
    float* __restrict__ twt) {
  if ((int)blockIdx.x >= RMSB) {
    // weight-conversion role: four 8-float groups per thread
    int k0 = ((int)blockIdx.x - RMSB) * 1024 + (int)threadIdx.x;
    const float4* s = (const float4*)w1f;
#pragma unroll
    for (int i = 0; i < 4; ++i) {
      int k = k0 + i * 256;
      if (k < N81) ((int4*)w1b)[k] = cvt8(s[2 * k], s[2 * k + 1]);
    }
    return;
  }
  const int lane = threadIdx.x & 63;
  const int t = blockIdx.x * 4 + (threadIdx.x >> 6);

  const float4* xr  = (const float4*)x + (size_t)t * 256 + lane * 4;
  const float4* nwr = (const float4*)norm_w + lane * 4;
  const float4* gbr = (const float4*)gate_b;
  float4 xv[4], nwv[4];
#pragma unroll
  for (int i = 0; i < 4; ++i) xv[i] = xr[i];
  float4 gb0 = gbr[0], gb1 = gbr[1];
#pragma unroll
  for (int i = 0; i < 4; ++i) nwv[i] = nwr[i];

  float ss = 0.f;
#pragma unroll
  for (int i = 0; i < 4; ++i)
    ss += xv[i].x * xv[i].x + xv[i].y * xv[i].y + xv[i].z * xv[i].z + xv[i].w * xv[i].w;
#pragma unroll
  for (int m = 1; m < 64; m <<= 1) ss += __shfl_xor(ss, m);
  const float sc = rsqrtf(ss * (1.0f / DDIM) + 1.1920929e-07f);

  float4 h[4];
#pragma unroll
  for (int i = 0; i < 4; ++i) {
    h[i].x = xv[i].x * sc * nwv[i].x;
    h[i].y = xv[i].y * sc * nwv[i].y;
    h[i].z = xv[i].z * sc * nwv[i].z;
    h[i].w = xv[i].w * sc * nwv[i].w;
  }
  int4* hw = (int4*)(hb + (size_t)t * DDIM + lane * 16);
  hw[0] = cvt8(h[0], h[1]);
  hw[1] = cvt8(h[2], h[3]);

  float p[NEXP];
#pragma unroll
  for (int e = 0; e < NEXP; ++e) {
    const float4* g4 = (const float4*)gate_w + e * 256 + lane * 4;
    float4 a = g4[0], b = g4[1], c = g4[2], d = g4[3];
    p[e] = h[0].x * a.x + h[0].y * a.y + h[0].z * a.z + h[0].w * a.w
         + h[1].x * b.x + h[1].y * b.y + h[1].z * b.z + h[1].w * b.w
         + h[2].x * c.x + h[2].y * c.y + h[2].z * c.z + h[2].w * c.w
         + h[3].x * d.x + h[3].y * d.y + h[3].z * d.z + h[3].w * d.w;
  }
#pragma unroll
  for (int m = 1; m < 64; m <<= 1) {
#pragma unroll
    for (int e = 0; e < NEXP; ++e) p[e] += __shfl_xor(p[e], m);
  }
  p[0] += gb0.x; p[1] += gb0.y; p[2] += gb0.z; p[3] += gb0.w;
  p[4] += gb1.x; p[5] += gb1.y; p[6] += gb1.z; p[7] += gb1.w;

  if (lane == 0) {
    int i0 = 0; float v0 = p[0];
#pragma unroll
    for (int e = 1; e < NEXP; ++e) if (p[e] > v0) { v0 = p[e]; i0 = e; }
    int i1 = -1; float v1 = -3.4e38f;
#pragma unroll
    for (int e = 0; e < NEXP; ++e) if (e != i0 && p[e] > v1) { v1 = p[e]; i1 = e; }
    float e1 = __expf(v1 - v0);
    float w0 = 1.f / (1.f + e1);
    int2 ip; ip.x = i0; ip.y = i1;
    float2 wp; wp.x = w0; wp.y = e1 * w0;
    ((int2*)tidx)[t] = ip;
    ((float2*)twt)[t] = wp;
  }
}

// ---------------- K2: scheduler — deterministic, wave-parallel scan -----------
__global__ __launch_bounds__(512) void k_sched(
    const int* __restrict__ tidx, int* __restrict__ meta,
    int* __restrict__ tl, int* __restrict__ rows, int* __restrict__ sof) {
  __shared__ unsigned short cnt[256][NEXP];   // 4 KB
  __shared__ int off[NEXP];
  __shared__ int tot[NEXP];
  const int tid = threadIdx.x;
  int e_[16], rel_[16];
  if (tid < 256) {
#pragma unroll
    for (int k = 0; k < 16; ++k) e_[k] = tidx[tid * 16 + k];
#pragma unroll
    for (int k = 0; k < 16; ++k) {
      int r = 0;
#pragma unroll
      for (int j2 = 0; j2 < 16; ++j2)
        if (j2 < k) r += (e_[j2] == e_[k]) ? 1 : 0;
      rel_[k] = r;
    }
#pragma unroll
    for (int e = 0; e < NEXP; ++e) {
      int c = 0;
#pragma unroll
      for (int k = 0; k < 16; ++k) c += (e_[k] == e) ? 1 : 0;
      cnt[tid][e] = (unsigned short)c;
    }
  }
  __syncthreads();
  // wave-parallel exclusive scan: wave `we` scans expert `we`'s 256 counts
  {
    const int we = tid >> 6, lane = tid & 63;
    int carry = 0;
#pragma unroll
    for (int chunk = 0; chunk < 4; ++chunk) {
      int i = chunk * 64 + lane;
      int c = (int)cnt[i][we];
      int s = c;
#pragma unroll
      for (int o = 1; o < 64; o <<= 1) {
        int t2 = __shfl_up(s, o);
        if (lane >= o) s += t2;
      }
      cnt[i][we] = (unsigned short)(s - c + carry);  // exclusive prefix
      carry += __shfl(s, 63);
    }
    if (lane == 0) tot[we] = carry;
  }
  __syncthreads();
  if (tid == 0) {
    int acc = 0, nt = 0;
    for (int e = 0; e < NEXP; ++e) {
      meta[8 + e] = acc; off[e] = acc;
      int c = tot[e]; acc += c;
      int ntile = (c + 127) >> 7;
      for (int r = 0; r < ntile; ++r) tl[nt++] = (e << 8) | r;
    }
    meta[16] = acc;
    meta[25] = nt;
  }
  __syncthreads();
  if (tid < 256) {
#pragma unroll
    for (int k = 0; k < 16; ++k) {
      int i = tid * 16 + k;
      int e = e_[k];
      int slot = off[e] + (int)cnt[tid][e] + rel_[k];
      rows[slot] = i >> 1;
      sof[i] = slot;
    }
  }
}

// ---------------- K4: GEMM1, BK=32 dbuf + counted vmcnt, conflict-free swz ----
// Swizzle swz(row) = (row>>1)&3 gives 2-way max bank aliasing on fragment
// reads (free per m136); R17's (row&3) was 4-way (2.29M conflict cycles).
__global__ __launch_bounds__(256, 4) void k_gemm1(
    const unsigned short* __restrict__ hb, const unsigned short* __restrict__ w1b,
    const float* __restrict__ mlp1_b, const int* __restrict__ meta,
    const int* __restrict__ tl, const int* __restrict__ rows,
    const float* __restrict__ w2f, unsigned short* __restrict__ w2b,
    unsigned short* __restrict__ actb) {
  const int bid = blockIdx.x;
  const int tid = threadIdx.x, lane = tid & 63, wid = tid >> 6;
  if (bid >= G1TOT) {
    // w2 conversion role: four 8-float groups per thread
    int k0 = (bid - G1TOT) * 1024 + tid;
    const float4* s = (const float4*)w2f;
#pragma unroll
    for (int i = 0; i < 4; ++i) {
      int k = k0 + i * 256;
      if (k < N82) ((int4*)w2b)[k] = cvt8(s[2 * k], s[2 * k + 1]);
    }
    return;
  }
  const int nt = meta[25];
  const int total = nt * (TWOI / 128);
  if (bid >= total) return;
  const int j = xcd_swz(bid, total);
  const int ct = j / nt;
  const int tile = tl[j - ct * nt];
  const int e = tile >> 8, rt = tile & 255;
  const int offs = meta[8 + e];
  const int n_e = meta[9 + e] - offs;

  __shared__ unsigned short As[2][128][32];   // 8 KB x2
  __shared__ unsigned short Bs[2][128][32];   // 8 KB x2
  __shared__ int srow[128];
  if (tid < 128) srow[tid] = rows[offs + min(rt * 128 + tid, n_e - 1)];
  __syncthreads();

  // staging: slot s = j*256+tid -> LDS elems s*8; row = s>>2, col chunk tid&3;
  // source col XOR-swizzled by (row>>1)&3 (both-sides swizzle, rule #21).
  const int r0  = tid >> 2;                            // 0..63
  const int csw = (((tid & 3) ^ ((r0 >> 1) & 3)) << 3);  // elem offset in row
  const unsigned short* w1e = w1b + (size_t)e * TWOI * DDIM;
  const unsigned short* gA0 = hb + (size_t)srow[r0] * DDIM + csw;
  const unsigned short* gA1 = hb + (size_t)srow[64 + r0] * DDIM + csw;
  const unsigned short* gB0 = w1e + (size_t)(ct * 128 + r0) * DDIM + csw;
  const unsigned short* gB1 = w1e + (size_t)(ct * 128 + 64 + r0) * DDIM + csw;

#define G1_STAGE(BUF, KT) {                                                    \
    gl2lds16(gA0 + (KT) * 32, &As[BUF][0][0] + tid * 8);                       \
    gl2lds16(gA1 + (KT) * 32, &As[BUF][0][0] + 2048 + tid * 8);                \
    gl2lds16(gB0 + (KT) * 32, &Bs[BUF][0][0] + tid * 8);                       \
    gl2lds16(gB1 + (KT) * 32, &Bs[BUF][0][0] + 2048 + tid * 8);                \
  }

  f32x4 acc[4][4];
#pragma unroll
  for (int m = 0; m < 4; ++m)
#pragma unroll
    for (int n = 0; n < 4; ++n) acc[m][n] = (f32x4){0.f, 0.f, 0.f, 0.f};

  const int wr = wid >> 1, wc = wid & 1;
  const int lrow = lane & 15, kgrp = lane >> 4;   // kgrp = K-chunk 0..3
  const int NK = DDIM / 32;                       // 32 steps

  G1_STAGE(0, 0)
#pragma unroll
  for (int kt = 0; kt < NK; ++kt) {
    const int cur = kt & 1;
    if (kt + 1 < NK) {
      G1_STAGE(cur ^ 1, kt + 1)
      SCHEDB();
      VMCNT4();       // current buffer's 4 loads landed; next 4 stay in flight
    } else {
      VMCNT0();
    }
    SCHEDB();
    WGBAR();
    SCHEDB();
    bf16x8 af[4], bfr[4];
#pragma unroll
    for (int m = 0; m < 4; ++m) {
      int row = wr * 64 + m * 16 + lrow;
      int chunk = kgrp ^ ((row >> 1) & 3);
      af[m] = *(const bf16x8*)&As[cur][row][chunk * 8];
    }
#pragma unroll
    for (int n = 0; n < 4; ++n) {
      int row = wc * 64 + n * 16 + lrow;
      int chunk = kgrp ^ ((row >> 1) & 3);
      bfr[n] = *(const bf16x8*)&Bs[cur][row][chunk * 8];
    }
#pragma unroll
    for (int m = 0; m < 4; ++m)
#pragma unroll
      for (int n = 0; n < 4; ++n)
        acc[m][n] = __builtin_amdgcn_mfma_f32_16x16x32_bf16(af[m], bfr[n], acc[m][n], 0, 0, 0);
    SCHEDB();
    WGBAR();
    SCHEDB();
  }
#undef G1_STAGE

  const float* b1e = mlp1_b + e * TWOI;
#pragma unroll
  for (int m = 0; m < 4; ++m) {
#pragma unroll
    for (int n = 0; n < 4; ++n) {
      int cg = ct * 128 + wc * 64 + n * 16 + (lane & 15);
      float bias = b1e[cg];
#pragma unroll
      for (int j2 = 0; j2 < 4; ++j2) {
        float val = acc[m][n][j2] + bias;
        float part = __shfl_xor(val, 1);
        int rl = wr * 64 + m * 16 + ((lane >> 4) << 2) + j2;
        if (!(lane & 1)) {
          float glu = fminf(val, LIMITV);
          float lin = fminf(fmaxf(part, -LIMITV), LIMITV);
          float s = 1.f / (1.f + __expf(-ALPHAV * glu));
          float a = glu * s * (lin + 1.f);
          if (rt * 128 + rl < n_e)
            actb[(size_t)(offs + rt * 128 + rl) * IDIM + (cg >> 1)] = f2bf(a);
        }
      }
    }
  }
}

// ---------------- K5: GEMM2, K-split x2, single-buffered, 4 blocks/CU ---------
__global__ __launch_bounds__(256, 4) void k_gemm2(
    const unsigned short* __restrict__ actb, const unsigned short* __restrict__ w2b,
    const float* __restrict__ mlp2_b, const int* __restrict__ meta,
    const int* __restrict__ tl, unsigned short* __restrict__ ybuf) {
  const int nt = meta[25];
  const int totalK = nt * (DDIM / 128) * 2;
  const int bid = blockIdx.x;
  if (bid >= totalK) return;
  const int j = xcd_swz(bid, totalK);
  const int kp = j & 1;          // K half: 0 -> [0,512), 1 -> [512,1024)
  const int jt = j >> 1;
  const int ct = jt / nt;
  const int tile = tl[jt - ct * nt];
  const int e = tile >> 8, rt = tile & 255;
  const int offs = meta[8 + e];
  const int n_e = meta[9 + e] - offs;
  const int tid = threadIdx.x, lane = tid & 63, wid = tid >> 6;

  __shared__ unsigned short As[128][64];
  __shared__ unsigned short Bs[128][64];

  const int rloc = tid >> 3;
  const int csw  = (((tid & 7) ^ (rloc & 7)) << 3);
  const int koff = kp * 512;     // element offset into K
  const unsigned short* gA[4];
  const unsigned short* gB[4];
  const unsigned short* w2e = w2b + (size_t)e * DDIM * IDIM;
#pragma unroll
  for (int jj = 0; jj < 4; ++jj) {
    gA[jj] = actb + (size_t)(offs + min(rt * 128 + jj * 32 + rloc, n_e - 1)) * IDIM + koff + csw;
    gB[jj] = w2e + (size_t)(ct * 128 + jj * 32 + rloc) * IDIM + koff + csw;
  }

#define G2_STAGE(KT)                                                           \
  _Pragma("unroll") for (int jj = 0; jj < 4; ++jj) {                           \
    gl2lds16(gA[jj] + (KT) * 64, &As[0][0] + jj * 2048 + tid * 8);             \
    gl2lds16(gB[jj] + (KT) * 64, &Bs[0][0] + jj * 2048 + tid * 8);             \
  }

  f32x4 acc[4][4];
#pragma unroll
  for (int m = 0; m < 4; ++m)
#pragma unroll
    for (int n = 0; n < 4; ++n) acc[m][n] = (f32x4){0.f, 0.f, 0.f, 0.f};

  const int wr = wid >> 1, wc = wid & 1;
  const int lrow = lane & 15, ksub = (lane >> 4) * 8;
  const int NK = 512 / 64;   // 8 K-steps per half

#pragma unroll
  for (int kt = 0; kt < NK; ++kt) {
    G2_STAGE(kt)
    VMCNT0();
    BARRIER();
#pragma unroll
    for (int kk = 0; kk < 2; ++kk) {
      bf16x8 af[4], bfr[4];
#pragma unroll
      for (int m = 0; m < 4; ++m) {
        int row = wr * 64 + m * 16 + lrow;
        int chunk = ((kk * 32 + ksub) >> 3) ^ (row & 7);
        af[m] = *(const bf16x8*)&As[row][chunk * 8];
      }
#pragma unroll
      for (int n = 0; n < 4; ++n) {
        int row = wc * 64 + n * 16 + lrow;
        int chunk = ((kk * 32 + ksub) >> 3) ^ (row & 7);
        bfr[n] = *(const bf16x8*)&Bs[row][chunk * 8];
      }
#pragma unroll
      for (int m = 0; m < 4; ++m)
#pragma unroll
        for (int n = 0; n < 4; ++n)
          acc[m][n] = __builtin_amdgcn_mfma_f32_16x16x32_bf16(af[m], bfr[n], acc[m][n], 0, 0, 0);
    }
    BARRIER();
  }
#undef G2_STAGE

  const float* b2e = mlp2_b + e * DDIM;
  unsigned short* yh = ybuf + (size_t)kp * TNUM * KSEL * DDIM;
#pragma unroll
  for (int m = 0; m < 4; ++m) {
#pragma unroll
    for (int n = 0; n < 4; ++n) {
      int d = ct * 128 + wc * 64 + n * 16 + (lane & 15);
      float bias = kp ? 0.f : b2e[d];
#pragma unroll
      for (int j2 = 0; j2 < 4; ++j2) {
        int rl = wr * 64 + m * 16 + ((lane >> 4) << 2) + j2;
        if (rt * 128 + rl < n_e)
          yh[(size_t)(offs + rt * 128 + rl) * DDIM + d] = f2bf(acc[m][n][j2] + bias);
      }
    }
  }
}

// ---------------- K6: combine (sums 2 K-partials per slot, no atomics) --------
__global__ __launch_bounds__(256) void k_combine(
    const float* __restrict__ x, const unsigned short* __restrict__ ybuf,
    const int* __restrict__ sof, const float* __restrict__ twt,
    float* __restrict__ out) {
  int t = blockIdx.x, tid = threadIdx.x;
  int s0 = sof[2 * t], s1 = sof[2 * t + 1];
  float w0 = twt[2 * t], w1 = twt[2 * t + 1];
  const size_t H = (size_t)TNUM * KSEL * DDIM;
  float4 xv = ((const float4*)x)[t * 256 + tid];
  float4 a0 = ld4bf(ybuf + (size_t)s0 * DDIM + tid * 4);
  float4 a1 = ld4bf(ybuf + H + (size_t)s0 * DDIM + tid * 4);
  float4 b0 = ld4bf(ybuf + (size_t)s1 * DDIM + tid * 4);
  float4 b1 = ld4bf(ybuf + H + (size_t)s1 * DDIM + tid * 4);
  float4 o;
  o.x = xv.x + w0 * (a0.x + a1.x) + w1 * (b0.x + b1.x);
  o.y = xv.y + w0 * (a0.y + a1.y) + w1 * (b0.y + b1.y);
  o.z = xv.z + w0 * (a0.z + a1.z) + w1 * (b0.z + b1.z);
  o.w = xv.w + w0 * (a0.w + a1.w) + w1 * (b0.w + b1.w);
  ((float4*)out)[t * 256 + tid] = o;
}

extern "C" void kernel_launch(void* const* d_in, const int* in_sizes, int n_in,
                              void* d_out, int out_size, void* d_ws, size_t ws_size,
                              hipStream_t stream) {
  const float* x      = (const float*)d_in[0];
  const float* norm_w = (const float*)d_in[1];
  const float* gate_w = (const float*)d_in[2];
  const float* gate_b = (const float*)d_in[3];
  const float* mlp1_w = (const float*)d_in[4];
  const float* mlp1_b = (const float*)d_in[5];
  const float* mlp2_w = (const float*)d_in[6];
  const float* mlp2_b = (const float*)d_in[7];
  float* out = (float*)d_out;

  char* w = (char*)d_ws;
  unsigned short* w1b = (unsigned short*)w; w += (size_t)NEXP * TWOI * DDIM * 2;
  unsigned short* w2b = (unsigned short*)w; w += (size_t)NEXP * DDIM * IDIM * 2;
  unsigned short* hb  = (unsigned short*)w; w += (size_t)TNUM * DDIM * 2;
  unsigned short* actb = (unsigned short*)w; w += (size_t)TNUM * KSEL * IDIM * 2;
  unsigned short* ybuf = (unsigned short*)w; w += (size_t)2 * TNUM * KSEL * DDIM * 2;
  int*   tidx = (int*)w;  w += TNUM * KSEL * 4;
  float* twt  = (float*)w; w += TNUM * KSEL * 4;
  int*   sof  = (int*)w;  w += TNUM * KSEL * 4;
  int*   rows = (int*)w;  w += TNUM * KSEL * 4;
  int*   meta = (int*)w;  w += 32 * 4;
  int*   tl   = (int*)w;  w += 64 * 4;

  k_rms_cvt<<<RMSB + N81 / 1024, 256, 0, stream>>>(x, norm_w, gate_w, gate_b,
                                                   mlp1_w, w1b, hb, tidx, twt);
  k_sched<<<1, 512, 0, stream>>>(tidx, meta, tl, rows, sof);
  k_gemm1<<<G1TOT + N82 / 1024, 256, 0, stream>>>(hb, w1b, mlp1_b, meta, tl, rows,
                                                  mlp2_w, w2b, actb);
  k_gemm2<<<G2TOT, 256, 0, stream>>>(actb, w2b, mlp2_b, meta, tl, ybuf);
  k_combine<<<TNUM, 256, 0, stream>>>(x, ybuf, sof, twt, out);
}

// Round 19
// 100.184 us; speedup vs baseline: 1.0508x; 1.0440x over previous
//
#include <hip/hip_runtime.h>
#include <stdint.h>

#define TNUM 2048
#define DDIM 1024
#define NEXP 8
#define KSEL 2
#define IDIM 1024
#define TWOI 2048
#define LIMITV 7.0f
#define ALPHAV 1.702f
#define ROWT_MAX 40   // sum_e ceil(n_e/128) <= 39 < 40 (provable)
#define RMSB (TNUM / 4)               // 512 rms blocks (wave-per-token)
#define N81 (NEXP * TWOI * DDIM / 8)  // w1 8-float groups = 2097152
#define N82 (NEXP * DDIM * IDIM / 8)  // w2 8-float groups = 1048576
#define G1TOT (ROWT_MAX * (TWOI / 128))  // 640 gemm1 tile slots
#define G2TOT (2 * ROWT_MAX * (DDIM / 128))  // 640 gemm2 slots (K-split x2)

typedef __attribute__((ext_vector_type(8))) short bf16x8;
typedef __attribute__((ext_vector_type(4))) float f32x4;

#define VMCNT0() asm volatile("s_waitcnt vmcnt(0)" ::: "memory")
#define BARRIER() asm volatile("s_barrier" ::: "memory")

__device__ __forceinline__ unsigned short f2bf(float f) {
  unsigned u = __float_as_uint(f);
  u += 0x7FFF + ((u >> 16) & 1);   // round-to-nearest-even
  return (unsigned short)(u >> 16);
}

__device__ __forceinline__ int4 cvt8(float4 a, float4 b) {
  union { unsigned short us[8]; int4 v; } o;
  o.us[0] = f2bf(a.x); o.us[1] = f2bf(a.y); o.us[2] = f2bf(a.z); o.us[3] = f2bf(a.w);
  o.us[4] = f2bf(b.x); o.us[5] = f2bf(b.y); o.us[6] = f2bf(b.z); o.us[7] = f2bf(b.w);
  return o.v;
}

__device__ __forceinline__ float4 ld4bf(const unsigned short* p) {
  int2 v = *(const int2*)p;
  unsigned a = (unsigned)v.x, b = (unsigned)v.y;
  float4 r;
  r.x = __uint_as_float((a & 0xFFFFu) << 16);
  r.y = __uint_as_float(a & 0xFFFF0000u);
  r.z = __uint_as_float((b & 0xFFFFu) << 16);
  r.w = __uint_as_float(b & 0xFFFF0000u);
  return r;
}

// Direct global->LDS async copy, 16B per lane (m97/m193 recipe).
__device__ __forceinline__ void gl2lds16(const void* g, void* l) {
  __builtin_amdgcn_global_load_lds(
      (__attribute__((address_space(1))) unsigned int*)(uintptr_t)g,
      (__attribute__((address_space(3))) unsigned int*)(uintptr_t)l, 16, 0, 0);
}

// Bijective chunked XCD swizzle (m204).
__device__ __forceinline__ int xcd_swz(int bid, int total) {
  int q = total >> 3, r = total & 7;
  int xcd = bid & 7, pos = bid >> 3;
  return (xcd < r ? xcd * (q + 1) : r * (q + 1) + (xcd - r) * q) + pos;
}

// ---------------- K1: RMSNorm + gate + top-2 (wave/token) ∥ w1 fp32->bf16 -----
__global__ __launch_bounds__(256) void k_rms_cvt(
    const float* __restrict__ x, const float* __restrict__ norm_w,
    const float* __restrict__ gate_w, const float* __restrict__ gate_b,
    const float* __restrict__ w1f, unsigned short* __restrict__ w1b,
    unsigned short* __restrict__ hb, int* __restrict__ tidx,
    float* __restrict__ twt) {
  if ((int)blockIdx.x >= RMSB) {
    // weight-conversion role: four 8-float groups per thread
    int k0 = ((int)blockIdx.x - RMSB) * 1024 + (int)threadIdx.x;
    const float4* s = (const float4*)w1f;
#pragma unroll
    for (int i = 0; i < 4; ++i) {
      int k = k0 + i * 256;
      if (k < N81) ((int4*)w1b)[k] = cvt8(s[2 * k], s[2 * k + 1]);
    }
    return;
  }
  const int lane = threadIdx.x & 63;
  const int t = blockIdx.x * 4 + (threadIdx.x >> 6);

  const float4* xr  = (const float4*)x + (size_t)t * 256 + lane * 4;
  const float4* nwr = (const float4*)norm_w + lane * 4;
  const float4* gbr = (const float4*)gate_b;
  float4 xv[4], nwv[4];
#pragma unroll
  for (int i = 0; i < 4; ++i) xv[i] = xr[i];
  float4 gb0 = gbr[0], gb1 = gbr[1];
#pragma unroll
  for (int i = 0; i < 4; ++i) nwv[i] = nwr[i];

  float ss = 0.f;
#pragma unroll
  for (int i = 0; i < 4; ++i)
    ss += xv[i].x * xv[i].x + xv[i].y * xv[i].y + xv[i].z * xv[i].z + xv[i].w * xv[i].w;
#pragma unroll
  for (int m = 1; m < 64; m <<= 1) ss += __shfl_xor(ss, m);
  const float sc = rsqrtf(ss * (1.0f / DDIM) + 1.1920929e-07f);

  float4 h[4];
#pragma unroll
  for (int i = 0; i < 4; ++i) {
    h[i].x = xv[i].x * sc * nwv[i].x;
    h[i].y = xv[i].y * sc * nwv[i].y;
    h[i].z = xv[i].z * sc * nwv[i].z;
    h[i].w = xv[i].w * sc * nwv[i].w;
  }
  int4* hw = (int4*)(hb + (size_t)t * DDIM + lane * 16);
  hw[0] = cvt8(h[0], h[1]);
  hw[1] = cvt8(h[2], h[3]);

  float p[NEXP];
#pragma unroll
  for (int e = 0; e < NEXP; ++e) {
    const float4* g4 = (const float4*)gate_w + e * 256 + lane * 4;
    float4 a = g4[0], b = g4[1], c = g4[2], d = g4[3];
    p[e] = h[0].x * a.x + h[0].y * a.y + h[0].z * a.z + h[0].w * a.w
         + h[1].x * b.x + h[1].y * b.y + h[1].z * b.z + h[1].w * b.w
         + h[2].x * c.x + h[2].y * c.y + h[2].z * c.z + h[2].w * c.w
         + h[3].x * d.x + h[3].y * d.y + h[3].z * d.z + h[3].w * d.w;
  }
#pragma unroll
  for (int m = 1; m < 64; m <<= 1) {
#pragma unroll
    for (int e = 0; e < NEXP; ++e) p[e] += __shfl_xor(p[e], m);
  }
  p[0] += gb0.x; p[1] += gb0.y; p[2] += gb0.z; p[3] += gb0.w;
  p[4] += gb1.x; p[5] += gb1.y; p[6] += gb1.z; p[7] += gb1.w;

  if (lane == 0) {
    int i0 = 0; float v0 = p[0];
#pragma unroll
    for (int e = 1; e < NEXP; ++e) if (p[e] > v0) { v0 = p[e]; i0 = e; }
    int i1 = -1; float v1 = -3.4e38f;
#pragma unroll
    for (int e = 0; e < NEXP; ++e) if (e != i0 && p[e] > v1) { v1 = p[e]; i1 = e; }
    float e1 = __expf(v1 - v0);
    float w0 = 1.f / (1.f + e1);
    int2 ip; ip.x = i0; ip.y = i1;
    float2 wp; wp.x = w0; wp.y = e1 * w0;
    ((int2*)tidx)[t] = ip;
    ((float2*)twt)[t] = wp;
  }
}

// ---------------- K2: scheduler — deterministic, wave-parallel scan -----------
__global__ __launch_bounds__(512) void k_sched(
    const int* __restrict__ tidx, int* __restrict__ meta,
    int* __restrict__ tl, int* __restrict__ rows, int* __restrict__ sof) {
  __shared__ unsigned short cnt[256][NEXP];   // 4 KB
  __shared__ int off[NEXP];
  __shared__ int tot[NEXP];
  const int tid = threadIdx.x;
  int e_[16], rel_[16];
  if (tid < 256) {
#pragma unroll
    for (int k = 0; k < 16; ++k) e_[k] = tidx[tid * 16 + k];
#pragma unroll
    for (int k = 0; k < 16; ++k) {
      int r = 0;
#pragma unroll
      for (int j2 = 0; j2 < 16; ++j2)
        if (j2 < k) r += (e_[j2] == e_[k]) ? 1 : 0;
      rel_[k] = r;
    }
#pragma unroll
    for (int e = 0; e < NEXP; ++e) {
      int c = 0;
#pragma unroll
      for (int k = 0; k < 16; ++k) c += (e_[k] == e) ? 1 : 0;
      cnt[tid][e] = (unsigned short)c;
    }
  }
  __syncthreads();
  // wave-parallel exclusive scan: wave `we` scans expert `we`'s 256 counts
  {
    const int we = tid >> 6, lane = tid & 63;
    int carry = 0;
#pragma unroll
    for (int chunk = 0; chunk < 4; ++chunk) {
      int i = chunk * 64 + lane;
      int c = (int)cnt[i][we];
      int s = c;
#pragma unroll
      for (int o = 1; o < 64; o <<= 1) {
        int t2 = __shfl_up(s, o);
        if (lane >= o) s += t2;
      }
      cnt[i][we] = (unsigned short)(s - c + carry);  // exclusive prefix
      carry += __shfl(s, 63);
    }
    if (lane == 0) tot[we] = carry;
  }
  __syncthreads();
  if (tid == 0) {
    int acc = 0, nt = 0;
    for (int e = 0; e < NEXP; ++e) {
      meta[8 + e] = acc; off[e] = acc;
      int c = tot[e]; acc += c;
      int ntile = (c + 127) >> 7;
      for (int r = 0; r < ntile; ++r) tl[nt++] = (e << 8) | r;
    }
    meta[16] = acc;
    meta[25] = nt;
  }
  __syncthreads();
  if (tid < 256) {
#pragma unroll
    for (int k = 0; k < 16; ++k) {
      int i = tid * 16 + k;
      int e = e_[k];
      int slot = off[e] + (int)cnt[tid][e] + rel_[k];
      rows[slot] = i >> 1;
      sof[i] = slot;
    }
  }
}

// ---------------- K4: GEMM1, single-buffered, 4 blocks/CU ∥ w2 cvt ------------
__global__ __launch_bounds__(256, 4) void k_gemm1(
    const unsigned short* __restrict__ hb, const unsigned short* __restrict__ w1b,
    const float* __restrict__ mlp1_b, const int* __restrict__ meta,
    const int* __restrict__ tl, const int* __restrict__ rows,
    const float* __restrict__ w2f, unsigned short* __restrict__ w2b,
    unsigned short* __restrict__ actb) {
  const int bid = blockIdx.x;
  const int tid = threadIdx.x, lane = tid & 63, wid = tid >> 6;
  if (bid >= G1TOT) {
    // w2 conversion role: four 8-float groups per thread
    int k0 = (bid - G1TOT) * 1024 + tid;
    const float4* s = (const float4*)w2f;
#pragma unroll
    for (int i = 0; i < 4; ++i) {
      int k = k0 + i * 256;
      if (k < N82) ((int4*)w2b)[k] = cvt8(s[2 * k], s[2 * k + 1]);
    }
    return;
  }
  const int nt = meta[25];
  const int total = nt * (TWOI / 128);
  if (bid >= total) return;
  const int j = xcd_swz(bid, total);
  const int ct = j / nt;
  const int tile = tl[j - ct * nt];
  const int e = tile >> 8, rt = tile & 255;
  const int offs = meta[8 + e];
  const int n_e = meta[9 + e] - offs;

  __shared__ unsigned short As[128][64];   // 16 KB
  __shared__ unsigned short Bs[128][64];   // 16 KB
  __shared__ int srow[128];
  if (tid < 128) srow[tid] = rows[offs + min(rt * 128 + tid, n_e - 1)];
  __syncthreads();

  const int rloc = tid >> 3;                         // 0..31
  const int csw  = (((tid & 7) ^ (rloc & 7)) << 3);  // swizzled source col (elems)
  const unsigned short* gA[4];
  const unsigned short* gB[4];
  const unsigned short* w1e = w1b + (size_t)e * TWOI * DDIM;
#pragma unroll
  for (int jj = 0; jj < 4; ++jj) {
    gA[jj] = hb + (size_t)srow[jj * 32 + rloc] * DDIM + csw;
    gB[jj] = w1e + (size_t)(ct * 128 + jj * 32 + rloc) * DDIM + csw;
  }

#define G1_STAGE(KT)                                                           \
  _Pragma("unroll") for (int jj = 0; jj < 4; ++jj) {                           \
    gl2lds16(gA[jj] + (KT) * 64, &As[0][0] + jj * 2048 + tid * 8);             \
    gl2lds16(gB[jj] + (KT) * 64, &Bs[0][0] + jj * 2048 + tid * 8);             \
  }

  f32x4 acc[4][4];
#pragma unroll
  for (int m = 0; m < 4; ++m)
#pragma unroll
    for (int n = 0; n < 4; ++n) acc[m][n] = (f32x4){0.f, 0.f, 0.f, 0.f};

  const int wr = wid >> 1, wc = wid & 1;
  const int lrow = lane & 15, ksub = (lane >> 4) * 8;
  const int NK = DDIM / 64;

#pragma unroll
  for (int kt = 0; kt < NK; ++kt) {
    G1_STAGE(kt)
    VMCNT0();
    BARRIER();
#pragma unroll
    for (int kk = 0; kk < 2; ++kk) {
      bf16x8 af[4], bfr[4];
#pragma unroll
      for (int m = 0; m < 4; ++m) {
        int row = wr * 64 + m * 16 + lrow;
        int chunk = ((kk * 32 + ksub) >> 3) ^ (row & 7);
        af[m] = *(const bf16x8*)&As[row][chunk * 8];
      }
#pragma unroll
      for (int n = 0; n < 4; ++n) {
        int row = wc * 64 + n * 16 + lrow;
        int chunk = ((kk * 32 + ksub) >> 3) ^ (row & 7);
        bfr[n] = *(const bf16x8*)&Bs[row][chunk * 8];
      }
#pragma unroll
      for (int m = 0; m < 4; ++m)
#pragma unroll
        for (int n = 0; n < 4; ++n)
          acc[m][n] = __builtin_amdgcn_mfma_f32_16x16x32_bf16(af[m], bfr[n], acc[m][n], 0, 0, 0);
    }
    BARRIER();
  }
#undef G1_STAGE

  const float* b1e = mlp1_b + e * TWOI;
#pragma unroll
  for (int m = 0; m < 4; ++m) {
#pragma unroll
    for (int n = 0; n < 4; ++n) {
      int cg = ct * 128 + wc * 64 + n * 16 + (lane & 15);
      float bias = b1e[cg];
#pragma unroll
      for (int j2 = 0; j2 < 4; ++j2) {
        float val = acc[m][n][j2] + bias;
        float part = __shfl_xor(val, 1);
        int rl = wr * 64 + m * 16 + ((lane >> 4) << 2) + j2;
        if (!(lane & 1)) {
          float glu = fminf(val, LIMITV);
          float lin = fminf(fmaxf(part, -LIMITV), LIMITV);
          float s = 1.f / (1.f + __expf(-ALPHAV * glu));
          float a = glu * s * (lin + 1.f);
          if (rt * 128 + rl < n_e)
            actb[(size_t)(offs + rt * 128 + rl) * IDIM + (cg >> 1)] = f2bf(a);
        }
      }
    }
  }
}

// ---------------- K5: GEMM2, K-split x2, single-buffered, 4 blocks/CU ---------
__global__ __launch_bounds__(256, 4) void k_gemm2(
    const unsigned short* __restrict__ actb, const unsigned short* __restrict__ w2b,
    const float* __restrict__ mlp2_b, const int* __restrict__ meta,
    const int* __restrict__ tl, unsigned short* __restrict__ ybuf) {
  const int nt = meta[25];
  const int totalK = nt * (DDIM / 128) * 2;
  const int bid = blockIdx.x;
  if (bid >= totalK) return;
  const int j = xcd_swz(bid, totalK);
  const int kp = j & 1;          // K half: 0 -> [0,512), 1 -> [512,1024)
  const int jt = j >> 1;
  const int ct = jt / nt;
  const int tile = tl[jt - ct * nt];
  const int e = tile >> 8, rt = tile & 255;
  const int offs = meta[8 + e];
  const int n_e = meta[9 + e] - offs;
  const int tid = threadIdx.x, lane = tid & 63, wid = tid >> 6;

  __shared__ unsigned short As[128][64];
  __shared__ unsigned short Bs[128][64];

  const int rloc = tid >> 3;
  const int csw  = (((tid & 7) ^ (rloc & 7)) << 3);
  const int koff = kp * 512;     // element offset into K
  const unsigned short* gA[4];
  const unsigned short* gB[4];
  const unsigned short* w2e = w2b + (size_t)e * DDIM * IDIM;
#pragma unroll
  for (int jj = 0; jj < 4; ++jj) {
    gA[jj] = actb + (size_t)(offs + min(rt * 128 + jj * 32 + rloc, n_e - 1)) * IDIM + koff + csw;
    gB[jj] = w2e + (size_t)(ct * 128 + jj * 32 + rloc) * IDIM + koff + csw;
  }

#define G2_STAGE(KT)                                                           \
  _Pragma("unroll") for (int jj = 0; jj < 4; ++jj) {                           \
    gl2lds16(gA[jj] + (KT) * 64, &As[0][0] + jj * 2048 + tid * 8);             \
    gl2lds16(gB[jj] + (KT) * 64, &Bs[0][0] + jj * 2048 + tid * 8);             \
  }

  f32x4 acc[4][4];
#pragma unroll
  for (int m = 0; m < 4; ++m)
#pragma unroll
    for (int n = 0; n < 4; ++n) acc[m][n] = (f32x4){0.f, 0.f, 0.f, 0.f};

  const int wr = wid >> 1, wc = wid & 1;
  const int lrow = lane & 15, ksub = (lane >> 4) * 8;
  const int NK = 512 / 64;   // 8 K-steps per half

#pragma unroll
  for (int kt = 0; kt < NK; ++kt) {
    G2_STAGE(kt)
    VMCNT0();
    BARRIER();
#pragma unroll
    for (int kk = 0; kk < 2; ++kk) {
      bf16x8 af[4], bfr[4];
#pragma unroll
      for (int m = 0; m < 4; ++m) {
        int row = wr * 64 + m * 16 + lrow;
        int chunk = ((kk * 32 + ksub) >> 3) ^ (row & 7);
        af[m] = *(const bf16x8*)&As[row][chunk * 8];
      }
#pragma unroll
      for (int n = 0; n < 4; ++n) {
        int row = wc * 64 + n * 16 + lrow;
        int chunk = ((kk * 32 + ksub) >> 3) ^ (row & 7);
        bfr[n] = *(const bf16x8*)&Bs[row][chunk * 8];
      }
#pragma unroll
      for (int m = 0; m < 4; ++m)
#pragma unroll
        for (int n = 0; n < 4; ++n)
          acc[m][n] = __builtin_amdgcn_mfma_f32_16x16x32_bf16(af[m], bfr[n], acc[m][n], 0, 0, 0);
    }
    BARRIER();
  }
#undef G2_STAGE

  const float* b2e = mlp2_b + e * DDIM;
  unsigned short* yh = ybuf + (size_t)kp * TNUM * KSEL * DDIM;
#pragma unroll
  for (int m = 0; m < 4; ++m) {
#pragma unroll
    for (int n = 0; n < 4; ++n) {
      int d = ct * 128 + wc * 64 + n * 16 + (lane & 15);
      float bias = kp ? 0.f : b2e[d];
#pragma unroll
      for (int j2 = 0; j2 < 4; ++j2) {
        int rl = wr * 64 + m * 16 + ((lane >> 4) << 2) + j2;
        if (rt * 128 + rl < n_e)
          yh[(size_t)(offs + rt * 128 + rl) * DDIM + d] = f2bf(acc[m][n][j2] + bias);
      }
    }
  }
}

// ---------------- K6: combine (sums 2 K-partials per slot, no atomics) --------
__global__ __launch_bounds__(256) void k_combine(
    const float* __restrict__ x, const unsigned short* __restrict__ ybuf,
    const int* __restrict__ sof, const float* __restrict__ twt,
    float* __restrict__ out) {
  int t = blockIdx.x, tid = threadIdx.x;
  int s0 = sof[2 * t], s1 = sof[2 * t + 1];
  float w0 = twt[2 * t], w1 = twt[2 * t + 1];
  const size_t H = (size_t)TNUM * KSEL * DDIM;
  float4 xv = ((const float4*)x)[t * 256 + tid];
  float4 a0 = ld4bf(ybuf + (size_t)s0 * DDIM + tid * 4);
  float4 a1 = ld4bf(ybuf + H + (size_t)s0 * DDIM + tid * 4);
  float4 b0 = ld4bf(ybuf + (size_t)s1 * DDIM + tid * 4);
  float4 b1 = ld4bf(ybuf + H + (size_t)s1 * DDIM + tid * 4);
  float4 o;
  o.x = xv.x + w0 * (a0.x + a1.x) + w1 * (b0.x + b1.x);
  o.y = xv.y + w0 * (a0.y + a1.y) + w1 * (b0.y + b1.y);
  o.z = xv.z + w0 * (a0.z + a1.z) + w1 * (b0.z + b1.z);
  o.w = xv.w + w0 * (a0.w + a1.w) + w1 * (b0.w + b1.w);
  ((float4*)out)[t * 256 + tid] = o;
}

extern "C" void kernel_launch(void* const* d_in, const int* in_sizes, int n_in,
                              void* d_out, int out_size, void* d_ws, size_t ws_size,
                              hipStream_t stream) {
  const float* x      = (const float*)d_in[0];
  const float* norm_w = (const float*)d_in[1];
  const float* gate_w = (const float*)d_in[2];
  const float* gate_b = (const float*)d_in[3];
  const float* mlp1_w = (const float*)d_in[4];
  const float* mlp1_b = (const float*)d_in[5];
  const float* mlp2_w = (const float*)d_in[6];
  const float* mlp2_b = (const float*)d_in[7];
  float* out = (float*)d_out;

  char* w = (char*)d_ws;
  unsigned short* w1b = (unsigned short*)w; w += (size_t)NEXP * TWOI * DDIM * 2;
  unsigned short* w2b = (unsigned short*)w; w += (size_t)NEXP * DDIM * IDIM * 2;
  unsigned short* hb  = (unsigned short*)w; w += (size_t)TNUM * DDIM * 2;
  unsigned short* actb = (unsigned short*)w; w += (size_t)TNUM * KSEL * IDIM * 2;
  unsigned short* ybuf = (unsigned short*)w; w += (size_t)2 * TNUM * KSEL * DDIM * 2;
  int*   tidx = (int*)w;  w += TNUM * KSEL * 4;
  float* twt  = (float*)w; w += TNUM * KSEL * 4;
  int*   sof  = (int*)w;  w += TNUM * KSEL * 4;
  int*   rows = (int*)w;  w += TNUM * KSEL * 4;
  int*   meta = (int*)w;  w += 32 * 4;
  int*   tl   = (int*)w;  w += 64 * 4;

  k_rms_cvt<<<RMSB + N81 / 1024, 256, 0, stream>>>(x, norm_w, gate_w, gate_b,
                                                   mlp1_w, w1b, hb, tidx, twt);
  k_sched<<<1, 512, 0, stream>>>(tidx, meta, tl, rows, sof);
  k_gemm1<<<G1TOT + N82 / 1024, 256, 0, stream>>>(hb, w1b, mlp1_b, meta, tl, rows,
                                                  mlp2_w, w2b, actb);
  k_gemm2<<<G2TOT, 256, 0, stream>>>(actb, w2b, mlp2_b, meta, tl, ybuf);
  k_combine<<<TNUM, 256, 0, stream>>>(x, ybuf, sof, twt, out);
}